// Round 6
// baseline (298.540 us; speedup 1.0000x reference)
//
#include <hip/hip_runtime.h>

#define N_NODES 50000
#define N_EDGES 800000
#define IN_FEAT 256
#define OUT_FEAT 128
#define P_EDGE 0.2f
#define P_NODE 0.1f
#define BN_EPS 1e-5f
#define CAP 64            // ushort slots per dst bucket = 128 B (max kept in-degree ~36)
#define GEMM_BLOCKS 782   // ceil(50000/64)
#define EDGE_BLOCKS 3125  // 800000/256
#define ZERO_BLOCKS 98    // 400000 B / (256*16)
#define PREPW_BLOCKS 128  // 32768/256
#define AGG_BLOCKS 1024
#define FIN_BLOCKS 8

typedef __bf16 bf16x8 __attribute__((ext_vector_type(8)));
typedef float floatx4 __attribute__((ext_vector_type(4)));

__device__ inline float bflo(unsigned u) { return __uint_as_float(u << 16); }
__device__ inline float bfhi(unsigned u) { return __uint_as_float(u & 0xffff0000u); }

// ---------------- init: zero deg counters + W (KxN fp32) -> Wt (NxK bf16) ----------------
__global__ __launch_bounds__(256) void k_init(const float* __restrict__ W,
    uint4* __restrict__ zero_base, __bf16* __restrict__ Wt) {
  if (blockIdx.x < ZERO_BLOCKS) {
    int i = blockIdx.x * 256 + threadIdx.x;
    if (i < 25000) zero_base[i] = make_uint4(0u, 0u, 0u, 0u);
  } else {
    int idx = (blockIdx.x - ZERO_BLOCKS) * 256 + threadIdx.x;
    int k = idx >> 7, n = idx & 127;
    Wt[n * IN_FEAT + k] = (__bf16)W[idx];
  }
}

__device__ inline bf16x8 cvt8(float4 a, float4 b) {
  bf16x8 v;
  v[0] = (__bf16)a.x; v[1] = (__bf16)a.y; v[2] = (__bf16)a.z; v[3] = (__bf16)a.w;
  v[4] = (__bf16)b.x; v[5] = (__bf16)b.y; v[6] = (__bf16)b.z; v[7] = (__bf16)b.w;
  return v;
}

// ---------------- GEMM: h = bf16(feat @ W), unscaled ----------------
// 4 waves/block; wave handles rows m0..m0+15, all 128 cols; MFMA 16x16x32.
__global__ __launch_bounds__(256) void k_gemm(const float* __restrict__ feat,
    const __bf16* __restrict__ Wt, __bf16* __restrict__ h) {
  const int lane = threadIdx.x & 63;
  const int wave = threadIdx.x >> 6;
  const int l16 = lane & 15;
  const int quad = lane >> 4;
  const int m0 = blockIdx.x * 64 + wave * 16;

  int mload = m0 + l16;
  if (mload >= N_NODES) mload = N_NODES - 1;

  bf16x8 a[8];
#pragma unroll
  for (int kk = 0; kk < 8; kk++) {
    const float4* p = (const float4*)(feat + (size_t)mload * IN_FEAT + kk * 32 + quad * 8);
    float4 f0 = p[0];
    float4 f1 = p[1];
    a[kk] = cvt8(f0, f1);
  }

  floatx4 acc[8];
#pragma unroll
  for (int g = 0; g < 8; g++) {
    const __bf16* wrow = Wt + (size_t)(g * 16 + l16) * IN_FEAT + quad * 8;
    floatx4 c = {0.f, 0.f, 0.f, 0.f};
#pragma unroll
    for (int kk = 0; kk < 8; kk++) {
      bf16x8 b = *(const bf16x8*)(wrow + kk * 32);
      c = __builtin_amdgcn_mfma_f32_16x16x32_bf16(a[kk], b, c, 0, 0, 0);
    }
    acc[g] = c;
  }

  const int rbase = m0 + quad * 4;
#pragma unroll
  for (int g = 0; g < 8; g++) {
#pragma unroll
    for (int r = 0; r < 4; r++) {
      int row = rbase + r;
      if (row < N_NODES)
        h[(size_t)row * OUT_FEAT + g * 16 + l16] = (__bf16)acc[g][r];
    }
  }
}

// ---------------- edge pass: deg count + ushort slot scatter ----------------
__global__ __launch_bounds__(256) void k_edge(const int* __restrict__ src,
    const int* __restrict__ dst, const float* __restrict__ er,
    unsigned* __restrict__ deg_src, unsigned* __restrict__ deg_dst,
    unsigned short* __restrict__ edge_src) {
  int e = blockIdx.x * 256 + threadIdx.x;
  if (er[e] >= P_EDGE) {
    int s = src[e], d = dst[e];
    atomicAdd(&deg_src[s], 1u);                  // fire-and-forget
    unsigned p = atomicAdd(&deg_dst[d], 1u);     // slot in d's bucket
    if (p < CAP) edge_src[(unsigned)d * CAP + p] = (unsigned short)s;
  }
}

// ---------------- aggregation: one wave per node, 4 edges in flight ----------------
// lane = g*16 + cl : group g handles edges i+g; cl covers cols cl*8..+7 (16 B bf16x8).
// Applies rsqrt(deg_src[s]) per edge, rsqrt(deg_dst[d]) + bias at the end.
// Fused BN partials: block writes psum/pssq[block*128 + c].
__global__ __launch_bounds__(256) void k_agg(const unsigned short* __restrict__ h,
    const unsigned short* __restrict__ edge_src, const unsigned* __restrict__ deg_src,
    const unsigned* __restrict__ deg_dst, const float* __restrict__ bias,
    float* __restrict__ out, float* __restrict__ psum, float* __restrict__ pssq) {
  const int wid = threadIdx.x >> 6;
  const int lane = threadIdx.x & 63;
  const int g = lane >> 4;
  const int cl = lane & 15;
  const int wave_global = blockIdx.x * 4 + wid;

  float b8[8];
#pragma unroll
  for (int j = 0; j < 8; j++) b8[j] = bias[cl * 8 + j];

  float s8[8], ss8[8];
#pragma unroll
  for (int j = 0; j < 8; j++) { s8[j] = 0.f; ss8[j] = 0.f; }

  unsigned cnt = deg_dst[wave_global];  // prefetch first node's degree
  for (int d = wave_global; d < N_NODES; d += AGG_BLOCKS * 4) {
    int dn = d + AGG_BLOCKS * 4;
    unsigned cnt_next = (dn < N_NODES) ? deg_dst[dn] : 0u;  // prefetch next
    unsigned lim = cnt > CAP ? CAP : cnt;
    const unsigned base = (unsigned)d * CAP;
    float acc[8];
#pragma unroll
    for (int j = 0; j < 8; j++) acc[j] = 0.f;

#pragma unroll 2
    for (unsigned i = 0; i < lim; i += 4) {
      unsigned e = i + (unsigned)g;
      bool valid = e < lim;
      unsigned idx = edge_src[base + (valid ? e : 0u)];
      unsigned dg = deg_src[idx];
      float r = valid ? rsqrtf((float)(dg ? dg : 1u)) : 0.f;
      uint4 u = *(const uint4*)(h + (size_t)idx * OUT_FEAT + cl * 8);
      acc[0] = fmaf(bflo(u.x), r, acc[0]);
      acc[1] = fmaf(bfhi(u.x), r, acc[1]);
      acc[2] = fmaf(bflo(u.y), r, acc[2]);
      acc[3] = fmaf(bfhi(u.y), r, acc[3]);
      acc[4] = fmaf(bflo(u.z), r, acc[4]);
      acc[5] = fmaf(bfhi(u.z), r, acc[5]);
      acc[6] = fmaf(bflo(u.w), r, acc[6]);
      acc[7] = fmaf(bfhi(u.w), r, acc[7]);
    }
    // reduce across the 4 edge-groups (lanes l, l^16, l^32, l^48 share cols)
#pragma unroll
    for (int j = 0; j < 8; j++) {
      acc[j] += __shfl_xor(acc[j], 16);
      acc[j] += __shfl_xor(acc[j], 32);
    }
    if (g == 0) {
      float sc = rsqrtf((float)(cnt ? cnt : 1u));
      float o[8];
#pragma unroll
      for (int j = 0; j < 8; j++) {
        o[j] = fmaf(acc[j], sc, b8[j]);
        s8[j] += o[j];
        ss8[j] = fmaf(o[j], o[j], ss8[j]);
      }
      float4 o0 = make_float4(o[0], o[1], o[2], o[3]);
      float4 o1 = make_float4(o[4], o[5], o[6], o[7]);
      *(float4*)(out + (size_t)d * OUT_FEAT + cl * 8) = o0;
      *(float4*)(out + (size_t)d * OUT_FEAT + cl * 8 + 4) = o1;
    }
    cnt = cnt_next;
  }

  // block-level stats partials
  __shared__ float ls[4][16][8], lss[4][16][8];
  if (g == 0) {
#pragma unroll
    for (int j = 0; j < 8; j++) { ls[wid][cl][j] = s8[j]; lss[wid][cl][j] = ss8[j]; }
  }
  __syncthreads();
  if (threadIdx.x < 128) {
    int pcl = threadIdx.x >> 3, pj = threadIdx.x & 7;  // col = pcl*8+pj = threadIdx.x
    float t = ls[0][pcl][pj] + ls[1][pcl][pj] + ls[2][pcl][pj] + ls[3][pcl][pj];
    float t2 = lss[0][pcl][pj] + lss[1][pcl][pj] + lss[2][pcl][pj] + lss[3][pcl][pj];
    psum[blockIdx.x * OUT_FEAT + threadIdx.x] = t;
    pssq[blockIdx.x * OUT_FEAT + threadIdx.x] = t2;
  }
}

// ---------------- reduce partials + finalize BN affine coefs ----------------
// block bg handles cols bg*16..+15; 256 thr = 16 cols x 16 slices
__global__ __launch_bounds__(256) void k_fin(const float* __restrict__ psum,
    const float* __restrict__ pssq, const float* __restrict__ gamma,
    const float* __restrict__ beta, float* __restrict__ a_coef,
    float* __restrict__ b_coef) {
  const int col16 = threadIdx.x & 15;
  const int slice = threadIdx.x >> 4;
  const int c = blockIdx.x * 16 + col16;
  float t = 0.f, t2 = 0.f;
  for (int b = slice; b < AGG_BLOCKS; b += 16) {
    t += psum[b * OUT_FEAT + c];
    t2 += pssq[b * OUT_FEAT + c];
  }
  __shared__ float S[16][17], S2[16][17];
  S[slice][col16] = t;
  S2[slice][col16] = t2;
  __syncthreads();
  if (threadIdx.x < 16) {
    float ts = 0.f, tss = 0.f;
#pragma unroll
    for (int s = 0; s < 16; s++) { ts += S[s][threadIdx.x]; tss += S2[s][threadIdx.x]; }
    int cc = blockIdx.x * 16 + threadIdx.x;
    float mean = ts * (1.0f / N_NODES);
    float var = tss * (1.0f / N_NODES) - mean * mean;
    float a = gamma[cc] * rsqrtf(var + BN_EPS);
    a_coef[cc] = a;
    b_coef[cc] = fmaf(-mean, a, beta[cc]);
  }
}

// ---------------- normalize + node dropout (in place on out) ----------------
__global__ __launch_bounds__(256) void k_norm(float* __restrict__ out,
    const float* __restrict__ node_rand, const float* __restrict__ a_coef,
    const float* __restrict__ b_coef) {
  const size_t total4 = (size_t)N_NODES * OUT_FEAT / 4;
  size_t i = (size_t)blockIdx.x * 256 + threadIdx.x;
  if (i < total4) {
    int c0 = (int)((i * 4) & 127);
    float4 v = ((const float4*)out)[i];
    float4 nr = ((const float4*)node_rand)[i];
    float4 a = *(const float4*)(a_coef + c0);
    float4 b = *(const float4*)(b_coef + c0);
    const float inv = 1.0f / (1.0f - P_NODE);
    float4 o;
    o.x = (nr.x >= P_NODE ? inv : 0.f) * fmaf(v.x, a.x, b.x);
    o.y = (nr.y >= P_NODE ? inv : 0.f) * fmaf(v.y, a.y, b.y);
    o.z = (nr.z >= P_NODE ? inv : 0.f) * fmaf(v.z, a.z, b.z);
    o.w = (nr.w >= P_NODE ? inv : 0.f) * fmaf(v.w, a.w, b.w);
    ((float4*)out)[i] = o;
  }
}

extern "C" void kernel_launch(void* const* d_in, const int* in_sizes, int n_in,
                              void* d_out, int out_size, void* d_ws, size_t ws_size,
                              hipStream_t stream) {
  const float* feat  = (const float*)d_in[0];
  const float* W     = (const float*)d_in[1];
  const float* bias  = (const float*)d_in[2];
  const float* gamma = (const float*)d_in[3];
  const float* beta  = (const float*)d_in[4];
  const int*   src   = (const int*)d_in[5];
  const int*   dst   = (const int*)d_in[6];
  const float* er    = (const float*)d_in[7];
  const float* nr    = (const float*)d_in[8];
  float* out = (float*)d_out;

  char* ws = (char*)d_ws;
  __bf16*         h        = (__bf16*)        (ws + 0);          // 12,800,000 B
  unsigned short* edge_src = (unsigned short*)(ws + 12800000);   //  6,400,000 B (50000 x CAP x 2)
  __bf16*         Wt       = (__bf16*)        (ws + 19200000);   //     65,536 B
  unsigned*       deg_src  = (unsigned*)      (ws + 19265536);   //    200,000 B [zeroed by k_init]
  unsigned*       deg_dst  = (unsigned*)      (ws + 19465536);   //    200,000 B [zeroed by k_init]
  float*          psum     = (float*)         (ws + 19665536);   //    524,288 B
  float*          pssq     = (float*)         (ws + 20189824);   //    524,288 B
  float*          a_coef   = (float*)         (ws + 20714112);   //        512 B
  float*          b_coef   = (float*)         (ws + 20714624);   //        512 B

  k_init<<<ZERO_BLOCKS + PREPW_BLOCKS, 256, 0, stream>>>(
      W, (uint4*)(ws + 19265536), Wt);
  k_gemm<<<GEMM_BLOCKS, 256, 0, stream>>>(feat, Wt, h);
  k_edge<<<EDGE_BLOCKS, 256, 0, stream>>>(src, dst, er, deg_src, deg_dst, edge_src);
  k_agg<<<AGG_BLOCKS, 256, 0, stream>>>((const unsigned short*)h, edge_src,
      deg_src, deg_dst, bias, out, psum, pssq);
  k_fin<<<FIN_BLOCKS, 256, 0, stream>>>(psum, pssq, gamma, beta, a_coef, b_coef);
  k_norm<<<(N_NODES * OUT_FEAT / 4 + 255) / 256, 256, 0, stream>>>(out, nr, a_coef, b_coef);
}

// Round 7
// 290.851 us; speedup vs baseline: 1.0264x; 1.0264x over previous
//
#include <hip/hip_runtime.h>

#define N_NODES 50000
#define N_EDGES 800000
#define IN_FEAT 256
#define OUT_FEAT 128
#define P_EDGE 0.2f
#define P_NODE 0.1f
#define BN_EPS 1e-5f
#define CAP 64            // ushort slots per dst bucket = 128 B (max kept in-degree ~36)
#define NPART 8           // XCD partitions
#define PART_N 6250       // N_NODES / NPART
#define ECHUNKS 128       // edge chunks
#define CHUNK_E 6250      // N_EDGES / ECHUNKS
#define GEMM_BLOCKS 782   // ceil(50000/64)
#define ZERO_BLOCKS 98    // 400000 B / (256*16)
#define PREPW_BLOCKS 128  // 32768/256
#define AGG_BLOCKS 1024
#define FIN_BLOCKS 8

typedef __bf16 bf16x8 __attribute__((ext_vector_type(8)));
typedef float floatx4 __attribute__((ext_vector_type(4)));

__device__ inline float bflo(unsigned u) { return __uint_as_float(u << 16); }
__device__ inline float bfhi(unsigned u) { return __uint_as_float(u & 0xffff0000u); }

// ---------------- init: zero deg counters + W (KxN fp32) -> Wt (NxK bf16) ----------------
__global__ __launch_bounds__(256) void k_init(const float* __restrict__ W,
    uint4* __restrict__ zero_base, __bf16* __restrict__ Wt) {
  if (blockIdx.x < ZERO_BLOCKS) {
    int i = blockIdx.x * 256 + threadIdx.x;
    if (i < 25000) zero_base[i] = make_uint4(0u, 0u, 0u, 0u);
  } else {
    int idx = (blockIdx.x - ZERO_BLOCKS) * 256 + threadIdx.x;
    int k = idx >> 7, n = idx & 127;
    Wt[n * IN_FEAT + k] = (__bf16)W[idx];
  }
}

// ---------------- edge pass: XCD-partitioned count + slot scatter ----------------
// part = blockIdx&7 -> node range [part*6250, +6250); chunk = blockIdx>>3 -> edge range.
// Each counter/bucket line is written by blocks of a single part (one XCD under
// round-robin dispatch) -> no cross-XCD line sharing on the write path.
__global__ __launch_bounds__(256) void k_edge(const int* __restrict__ src,
    const int* __restrict__ dst, const float* __restrict__ er,
    unsigned* __restrict__ deg_src, unsigned* __restrict__ deg_dst,
    unsigned short* __restrict__ edge_src) {
  const int part = blockIdx.x & (NPART - 1);
  const int chunk = blockIdx.x >> 3;
  const int nlo = part * PART_N;
  const int nhi = nlo + PART_N;
  const int e0 = chunk * CHUNK_E;
  for (int e = e0 + threadIdx.x; e < e0 + CHUNK_E; e += 256) {
    if (er[e] >= P_EDGE) {
      int s = src[e], d = dst[e];
      if (s >= nlo && s < nhi) atomicAdd(&deg_src[s], 1u);
      if (d >= nlo && d < nhi) {
        unsigned p = atomicAdd(&deg_dst[d], 1u);
        if (p < CAP) edge_src[(unsigned)d * CAP + p] = (unsigned short)s;
      }
    }
  }
}

__device__ inline bf16x8 cvt8(float4 a, float4 b) {
  bf16x8 v;
  v[0] = (__bf16)a.x; v[1] = (__bf16)a.y; v[2] = (__bf16)a.z; v[3] = (__bf16)a.w;
  v[4] = (__bf16)b.x; v[5] = (__bf16)b.y; v[6] = (__bf16)b.z; v[7] = (__bf16)b.w;
  return v;
}

// ---------------- GEMM: h = bf16( (feat @ W) * rsqrt(max(deg_src,1)) ) ----------------
// 4 waves/block; wave handles rows m0..m0+15, all 128 cols; MFMA 16x16x32.
__global__ __launch_bounds__(256) void k_gemm(const float* __restrict__ feat,
    const __bf16* __restrict__ Wt, const unsigned* __restrict__ deg_src,
    __bf16* __restrict__ h) {
  const int lane = threadIdx.x & 63;
  const int wave = threadIdx.x >> 6;
  const int l16 = lane & 15;
  const int quad = lane >> 4;
  const int m0 = blockIdx.x * 64 + wave * 16;

  int mload = m0 + l16;
  if (mload >= N_NODES) mload = N_NODES - 1;

  bf16x8 a[8];
#pragma unroll
  for (int kk = 0; kk < 8; kk++) {
    const float4* p = (const float4*)(feat + (size_t)mload * IN_FEAT + kk * 32 + quad * 8);
    float4 f0 = p[0];
    float4 f1 = p[1];
    a[kk] = cvt8(f0, f1);
  }

  floatx4 acc[8];
#pragma unroll
  for (int g = 0; g < 8; g++) {
    const __bf16* wrow = Wt + (size_t)(g * 16 + l16) * IN_FEAT + quad * 8;
    floatx4 c = {0.f, 0.f, 0.f, 0.f};
#pragma unroll
    for (int kk = 0; kk < 8; kk++) {
      bf16x8 b = *(const bf16x8*)(wrow + kk * 32);
      c = __builtin_amdgcn_mfma_f32_16x16x32_bf16(a[kk], b, c, 0, 0, 0);
    }
    acc[g] = c;
  }

  const int rbase = m0 + quad * 4;
  float s[4];
#pragma unroll
  for (int r = 0; r < 4; r++) {
    int row = rbase + r;
    unsigned dg = (row < N_NODES) ? deg_src[row] : 1u;
    s[r] = rsqrtf((float)(dg ? dg : 1u));
  }
#pragma unroll
  for (int g = 0; g < 8; g++) {
#pragma unroll
    for (int r = 0; r < 4; r++) {
      int row = rbase + r;
      if (row < N_NODES)
        h[(size_t)row * OUT_FEAT + g * 16 + l16] = (__bf16)(acc[g][r] * s[r]);
    }
  }
}

// ---------------- aggregation: one wave per node, 4 edges in flight ----------------
// lane = g*16 + cl : group g handles edges i+g; cl covers cols cl*8..+7 (16 B bf16x8).
// h is pre-scaled by rsqrt(deg_src); apply rsqrt(deg_dst) + bias at the end.
// Fused BN partials: block writes psum/pssq[block*128 + c].
__global__ __launch_bounds__(256) void k_agg(const unsigned short* __restrict__ h,
    const unsigned short* __restrict__ edge_src,
    const unsigned* __restrict__ deg_dst, const float* __restrict__ bias,
    float* __restrict__ out, float* __restrict__ psum, float* __restrict__ pssq) {
  const int wid = threadIdx.x >> 6;
  const int lane = threadIdx.x & 63;
  const int g = lane >> 4;
  const int cl = lane & 15;
  const int wave_global = blockIdx.x * 4 + wid;

  float b8[8];
#pragma unroll
  for (int j = 0; j < 8; j++) b8[j] = bias[cl * 8 + j];

  float s8[8], ss8[8];
#pragma unroll
  for (int j = 0; j < 8; j++) { s8[j] = 0.f; ss8[j] = 0.f; }

  unsigned cnt = deg_dst[wave_global];  // prefetch first node's degree
  for (int d = wave_global; d < N_NODES; d += AGG_BLOCKS * 4) {
    int dn = d + AGG_BLOCKS * 4;
    unsigned cnt_next = (dn < N_NODES) ? deg_dst[dn] : 0u;  // prefetch next
    unsigned lim = cnt > CAP ? CAP : cnt;
    const unsigned base = (unsigned)d * CAP;
    float acc[8];
#pragma unroll
    for (int j = 0; j < 8; j++) acc[j] = 0.f;

#pragma unroll 2
    for (unsigned i = 0; i < lim; i += 4) {
      unsigned e = i + (unsigned)g;
      bool valid = e < lim;
      unsigned idx = edge_src[base + (valid ? e : 0u)];
      float m = valid ? 1.f : 0.f;
      uint4 u = *(const uint4*)(h + (size_t)idx * OUT_FEAT + cl * 8);
      acc[0] = fmaf(bflo(u.x), m, acc[0]);
      acc[1] = fmaf(bfhi(u.x), m, acc[1]);
      acc[2] = fmaf(bflo(u.y), m, acc[2]);
      acc[3] = fmaf(bfhi(u.y), m, acc[3]);
      acc[4] = fmaf(bflo(u.z), m, acc[4]);
      acc[5] = fmaf(bfhi(u.z), m, acc[5]);
      acc[6] = fmaf(bflo(u.w), m, acc[6]);
      acc[7] = fmaf(bfhi(u.w), m, acc[7]);
    }
    // reduce across the 4 edge-groups (lanes l, l^16, l^32, l^48 share cols)
#pragma unroll
    for (int j = 0; j < 8; j++) {
      acc[j] += __shfl_xor(acc[j], 16);
      acc[j] += __shfl_xor(acc[j], 32);
    }
    if (g == 0) {
      float sc = rsqrtf((float)(cnt ? cnt : 1u));
      float o[8];
#pragma unroll
      for (int j = 0; j < 8; j++) {
        o[j] = fmaf(acc[j], sc, b8[j]);
        s8[j] += o[j];
        ss8[j] = fmaf(o[j], o[j], ss8[j]);
      }
      float4 o0 = make_float4(o[0], o[1], o[2], o[3]);
      float4 o1 = make_float4(o[4], o[5], o[6], o[7]);
      *(float4*)(out + (size_t)d * OUT_FEAT + cl * 8) = o0;
      *(float4*)(out + (size_t)d * OUT_FEAT + cl * 8 + 4) = o1;
    }
    cnt = cnt_next;
  }

  // block-level stats partials
  __shared__ float ls[4][16][8], lss[4][16][8];
  if (g == 0) {
#pragma unroll
    for (int j = 0; j < 8; j++) { ls[wid][cl][j] = s8[j]; lss[wid][cl][j] = ss8[j]; }
  }
  __syncthreads();
  if (threadIdx.x < 128) {
    int pcl = threadIdx.x >> 3, pj = threadIdx.x & 7;  // col = pcl*8+pj = threadIdx.x
    float t = ls[0][pcl][pj] + ls[1][pcl][pj] + ls[2][pcl][pj] + ls[3][pcl][pj];
    float t2 = lss[0][pcl][pj] + lss[1][pcl][pj] + lss[2][pcl][pj] + lss[3][pcl][pj];
    psum[blockIdx.x * OUT_FEAT + threadIdx.x] = t;
    pssq[blockIdx.x * OUT_FEAT + threadIdx.x] = t2;
  }
}

// ---------------- reduce partials + finalize BN affine coefs ----------------
// block bg handles cols bg*16..+15; 256 thr = 16 cols x 16 slices
__global__ __launch_bounds__(256) void k_fin(const float* __restrict__ psum,
    const float* __restrict__ pssq, const float* __restrict__ gamma,
    const float* __restrict__ beta, float* __restrict__ a_coef,
    float* __restrict__ b_coef) {
  const int col16 = threadIdx.x & 15;
  const int slice = threadIdx.x >> 4;
  const int c = blockIdx.x * 16 + col16;
  float t = 0.f, t2 = 0.f;
  for (int b = slice; b < AGG_BLOCKS; b += 16) {
    t += psum[b * OUT_FEAT + c];
    t2 += pssq[b * OUT_FEAT + c];
  }
  __shared__ float S[16][17], S2[16][17];
  S[slice][col16] = t;
  S2[slice][col16] = t2;
  __syncthreads();
  if (threadIdx.x < 16) {
    float ts = 0.f, tss = 0.f;
#pragma unroll
    for (int s = 0; s < 16; s++) { ts += S[s][threadIdx.x]; tss += S2[s][threadIdx.x]; }
    int cc = blockIdx.x * 16 + threadIdx.x;
    float mean = ts * (1.0f / N_NODES);
    float var = tss * (1.0f / N_NODES) - mean * mean;
    float a = gamma[cc] * rsqrtf(var + BN_EPS);
    a_coef[cc] = a;
    b_coef[cc] = fmaf(-mean, a, beta[cc]);
  }
}

// ---------------- normalize + node dropout (in place on out) ----------------
__global__ __launch_bounds__(256) void k_norm(float* __restrict__ out,
    const float* __restrict__ node_rand, const float* __restrict__ a_coef,
    const float* __restrict__ b_coef) {
  const size_t total4 = (size_t)N_NODES * OUT_FEAT / 4;
  size_t i = (size_t)blockIdx.x * 256 + threadIdx.x;
  if (i < total4) {
    int c0 = (int)((i * 4) & 127);
    float4 v = ((const float4*)out)[i];
    float4 nr = ((const float4*)node_rand)[i];
    float4 a = *(const float4*)(a_coef + c0);
    float4 b = *(const float4*)(b_coef + c0);
    const float inv = 1.0f / (1.0f - P_NODE);
    float4 o;
    o.x = (nr.x >= P_NODE ? inv : 0.f) * fmaf(v.x, a.x, b.x);
    o.y = (nr.y >= P_NODE ? inv : 0.f) * fmaf(v.y, a.y, b.y);
    o.z = (nr.z >= P_NODE ? inv : 0.f) * fmaf(v.z, a.z, b.z);
    o.w = (nr.w >= P_NODE ? inv : 0.f) * fmaf(v.w, a.w, b.w);
    ((float4*)out)[i] = o;
  }
}

extern "C" void kernel_launch(void* const* d_in, const int* in_sizes, int n_in,
                              void* d_out, int out_size, void* d_ws, size_t ws_size,
                              hipStream_t stream) {
  const float* feat  = (const float*)d_in[0];
  const float* W     = (const float*)d_in[1];
  const float* bias  = (const float*)d_in[2];
  const float* gamma = (const float*)d_in[3];
  const float* beta  = (const float*)d_in[4];
  const int*   src   = (const int*)d_in[5];
  const int*   dst   = (const int*)d_in[6];
  const float* er    = (const float*)d_in[7];
  const float* nr    = (const float*)d_in[8];
  float* out = (float*)d_out;

  char* ws = (char*)d_ws;
  __bf16*         h        = (__bf16*)        (ws + 0);          // 12,800,000 B
  unsigned short* edge_src = (unsigned short*)(ws + 12800000);   //  6,400,000 B (50000 x CAP x 2)
  __bf16*         Wt       = (__bf16*)        (ws + 19200000);   //     65,536 B
  unsigned*       deg_src  = (unsigned*)      (ws + 19265536);   //    200,000 B [zeroed by k_init]
  unsigned*       deg_dst  = (unsigned*)      (ws + 19465536);   //    200,000 B [zeroed by k_init]
  float*          psum     = (float*)         (ws + 19665536);   //    524,288 B
  float*          pssq     = (float*)         (ws + 20189824);   //    524,288 B
  float*          a_coef   = (float*)         (ws + 20714112);   //        512 B
  float*          b_coef   = (float*)         (ws + 20714624);   //        512 B

  k_init<<<ZERO_BLOCKS + PREPW_BLOCKS, 256, 0, stream>>>(
      W, (uint4*)(ws + 19265536), Wt);
  k_edge<<<ECHUNKS * NPART, 256, 0, stream>>>(src, dst, er, deg_src, deg_dst, edge_src);
  k_gemm<<<GEMM_BLOCKS, 256, 0, stream>>>(feat, Wt, deg_src, h);
  k_agg<<<AGG_BLOCKS, 256, 0, stream>>>((const unsigned short*)h, edge_src,
      deg_dst, bias, out, psum, pssq);
  k_fin<<<FIN_BLOCKS, 256, 0, stream>>>(psum, pssq, gamma, beta, a_coef, b_coef);
  k_norm<<<(N_NODES * OUT_FEAT / 4 + 255) / 256, 256, 0, stream>>>(out, nr, a_coef, b_coef);
}